// Round 15
// baseline (1336.307 us; speedup 1.0000x reference)
//
#include <hip/hip_runtime.h>

// ---------------------------------------------------------------------------
// BiSSM global block, MI355X — round 15: k=1 level folded into u-pass.
//   W1 = A@Bm (hi/lo k_mul)
//   X_2[t] = xn[t]@Bm^T + xn[t-/+1]@W1^T ; z = xn@gw^T       k_u2z
//   X_2k[t] = X_k[t] + X_k[t-/+k]@(A^k)^T, k=2..512          k_lvl x9 (r10 best)
//   Xsum[t] = X_f[t]+X_f[t-1024]@W + X_b[t]+X_b[t+1024]@W    k_cmb (W=A^1024)
//   out     = x + alpha*0.5*(Xsum@Cm^T)*sigmoid(z+gb)        k_fin2 (r14 fixed)
// k_lvl: round-10 proven (128x256, 8 waves 2x4, 2-buf 48KB, stage-early, one
// barrier/step, BLS-padded 4-phase bounce). k_u2z: same chassis, 128x128,
// 4 waves, 5 staged streams (80KB). Powers: k_sq x10 (3-pass hi/lo).
// ---------------------------------------------------------------------------

typedef short  bfrag __attribute__((ext_vector_type(8)));   // 8 x bf16
typedef float  ffrag __attribute__((ext_vector_type(4)));   // mfma acc
typedef float  f4    __attribute__((ext_vector_type(4)));
typedef short  s4v   __attribute__((ext_vector_type(4)));   // 4 x bf16

#define DEV static __device__ __forceinline__
#define Hn 768
#define FLS 132   // 128+4 pad (f32 bounce stride, 128-wide tiles)
#define BLS 260   // 256+4 pad (f32 bounce stride, 256-wide tiles)

DEV unsigned short f2bf(float f) {
  unsigned u = __float_as_uint(f);
  u += 0x7fffu + ((u >> 16) & 1u);            // round-to-nearest-even
  return (unsigned short)(u >> 16);
}
DEV float bf2f(unsigned short s) { return __uint_as_float(((unsigned)s) << 16); }

DEV ffrag mfma16(bfrag a, bfrag b, ffrag c) {
  return __builtin_amdgcn_mfma_f32_16x16x32_bf16(a, b, c, 0, 0, 0);
}

DEV void glds16(const unsigned short* g, unsigned short* l) {
  __builtin_amdgcn_global_load_lds(
      (const __attribute__((address_space(1))) unsigned int*)g,
      (__attribute__((address_space(3))) unsigned int*)l, 16, 0, 0);
}

union BF8 { bfrag v; unsigned short u[8]; };

// ---------------------------------------------------------------------------
// k_abuild: gridDim = (768, 4); task = blockIdx.y
//   task 1 additionally writes Bm^T as f32 (for W1 = A@Bm via k_mul).
__global__ __launch_bounds__(256) void k_abuild(
    const float* __restrict__ U, const float* __restrict__ V,
    const float* __restrict__ S, const float* __restrict__ Bm,
    const float* __restrict__ Cm, const float* __restrict__ gw,
    float* __restrict__ Af, float* __restrict__ AfT,
    unsigned short* __restrict__ Abf,
    unsigned short* __restrict__ Bmb, float* __restrict__ BmTf,
    unsigned short* __restrict__ Cmb, unsigned short* __restrict__ gwb,
    unsigned short* __restrict__ zp) {
  int i = blockIdx.x;
  int task = blockIdx.y;
  if (task == 0) {
    float u0 = U[i*4+0], u1 = U[i*4+1], u2 = U[i*4+2], u3 = U[i*4+3];
    for (int j = threadIdx.x; j < Hn; j += 256) {
      float a = u0*V[j*4+0] + u1*V[j*4+1] + u2*V[j*4+2] + u3*V[j*4+3]
              + S[i*Hn+j] - S[j*Hn+i];
      if (i == j) a += -(float)(i+1) / 768.0f;
      Af[i*Hn+j]  = a;
      AfT[j*Hn+i] = a;
      Abf[i*Hn+j] = f2bf(a);
    }
    if (i == 0) for (int j = threadIdx.x; j < 1024; j += 256) zp[j] = 0;
  } else if (task == 1) {
    for (int j = threadIdx.x; j < Hn; j += 256) {
      float v = Bm[i*Hn+j];
      Bmb[i*Hn+j]  = f2bf(v);
      BmTf[(long)j*Hn+i] = v;
    }
  } else {
    const float* src = (task==2) ? Cm : gw;
    unsigned short* dst = (task==2) ? Cmb : gwb;
    for (int j = threadIdx.x; j < Hn; j += 256) dst[i*Hn+j] = f2bf(src[i*Hn+j]);
  }
}

// ---------------------------------------------------------------------------
// k_rms: one wave per row (row = b*2048 + t); write xn in (t,b) order, bf16.
__global__ __launch_bounds__(256) void k_rms(
    const float* __restrict__ x, const float* __restrict__ scale,
    unsigned short* __restrict__ xn) {
  int row  = blockIdx.x * 4 + (threadIdx.x >> 6);
  int lane = threadIdx.x & 63;
  int b = row >> 11, t = row & 2047;
  const float* xr = x + (long)row * Hn;
  float v[12];
  float ss = 0.f;
#pragma unroll
  for (int j = 0; j < 12; ++j) { v[j] = xr[lane + j*64]; ss += v[j]*v[j]; }
#pragma unroll
  for (int off = 1; off < 64; off <<= 1) ss += __shfl_xor(ss, off);
  float inv = 1.0f / sqrtf(ss / 768.0f + 1e-8f);
  unsigned short* dst = xn + ((long)t * 8 + b) * Hn;
#pragma unroll
  for (int j = 0; j < 12; ++j) dst[lane + j*64] = f2bf(v[j] * inv * scale[lane + j*64]);
}

// ---------------------------------------------------------------------------
// k_sq: Z = X @ X, hi/lo bf16 (3 passes). Writes Z rm + Z^T rm f32 + bf16.
// grid (12, 6), 512 thr, tile 64x128.
__global__ __launch_bounds__(512) void k_sq(
    const float* __restrict__ X, const float* __restrict__ XT,
    float* __restrict__ Z, float* __restrict__ ZT,
    unsigned short* __restrict__ Zbf) {
  int tid = threadIdx.x, lane = tid & 63, w = tid >> 6;
  int mw = w >> 2, nw = w & 3, l15 = lane & 15, lhi = lane >> 4;
  int rb = blockIdx.x * 64, cb = blockIdx.y * 128;
  ffrag acc[2][2] = {};
  for (int kt = 0; kt < 24; ++kt) {
    int k0 = kt*32 + lhi*8;
    BF8 ah[2], al[2], bh[2], bl[2];
#pragma unroll
    for (int mt = 0; mt < 2; ++mt) {
      const f4* p = (const f4*)(X + (long)(rb + mw*32 + mt*16 + l15) * Hn + k0);
      f4 x0 = p[0], x1 = p[1];
#pragma unroll
      for (int j = 0; j < 8; ++j) {
        float f = (j < 4) ? x0[j] : x1[j-4];
        unsigned short h = f2bf(f);
        ah[mt].u[j] = h; al[mt].u[j] = f2bf(f - bf2f(h));
      }
    }
#pragma unroll
    for (int nt = 0; nt < 2; ++nt) {
      const f4* p = (const f4*)(XT + (long)(cb + nw*32 + nt*16 + l15) * Hn + k0);
      f4 x0 = p[0], x1 = p[1];
#pragma unroll
      for (int j = 0; j < 8; ++j) {
        float f = (j < 4) ? x0[j] : x1[j-4];
        unsigned short h = f2bf(f);
        bh[nt].u[j] = h; bl[nt].u[j] = f2bf(f - bf2f(h));
      }
    }
#pragma unroll
    for (int mt = 0; mt < 2; ++mt)
#pragma unroll
      for (int nt = 0; nt < 2; ++nt) {
        acc[mt][nt] = mfma16(ah[mt].v, bh[nt].v, acc[mt][nt]);
        acc[mt][nt] = mfma16(ah[mt].v, bl[nt].v, acc[mt][nt]);
        acc[mt][nt] = mfma16(al[mt].v, bh[nt].v, acc[mt][nt]);
      }
  }
#pragma unroll
  for (int mt = 0; mt < 2; ++mt)
#pragma unroll
    for (int nt = 0; nt < 2; ++nt)
#pragma unroll
      for (int q = 0; q < 4; ++q) {
        int grow = rb + mw*32 + mt*16 + lhi*4 + q;
        int gcol = cb + nw*32 + nt*16 + l15;
        float vv = acc[mt][nt][q];
        Z[(long)grow*Hn + gcol] = vv;
        ZT[(long)gcol*Hn + grow] = vv;
        Zbf[(long)grow*Hn + gcol] = f2bf(vv);
      }
}

// ---------------------------------------------------------------------------
// k_mul: Z = X @ Y (hi/lo bf16, 3 passes). YT = Y^T row-major. Writes f32
// Z/ZT if non-null + bf16 always. grid (12,6,1), 512 thr, tile 64x128.
__global__ __launch_bounds__(512) void k_mul(
    const float* __restrict__ X, const float* __restrict__ YT,
    float* __restrict__ Z, float* __restrict__ ZT,
    unsigned short* __restrict__ Zb) {
  int tid = threadIdx.x, lane = tid & 63, w = tid >> 6;
  int mw = w >> 2, nw = w & 3, l15 = lane & 15, lhi = lane >> 4;
  int rb = blockIdx.x * 64, cb = blockIdx.y * 128;
  ffrag acc[2][2] = {};
  for (int kt = 0; kt < 24; ++kt) {
    int k0 = kt*32 + lhi*8;
    BF8 ah[2], al[2], bh[2], bl[2];
#pragma unroll
    for (int mt = 0; mt < 2; ++mt) {
      const f4* p = (const f4*)(X + (long)(rb + mw*32 + mt*16 + l15) * Hn + k0);
      f4 x0 = p[0], x1 = p[1];
#pragma unroll
      for (int j = 0; j < 8; ++j) {
        float f = (j < 4) ? x0[j] : x1[j-4];
        unsigned short h = f2bf(f);
        ah[mt].u[j] = h; al[mt].u[j] = f2bf(f - bf2f(h));
      }
    }
#pragma unroll
    for (int nt = 0; nt < 2; ++nt) {
      const f4* p = (const f4*)(YT + (long)(cb + nw*32 + nt*16 + l15) * Hn + k0);
      f4 x0 = p[0], x1 = p[1];
#pragma unroll
      for (int j = 0; j < 8; ++j) {
        float f = (j < 4) ? x0[j] : x1[j-4];
        unsigned short h = f2bf(f);
        bh[nt].u[j] = h; bl[nt].u[j] = f2bf(f - bf2f(h));
      }
    }
#pragma unroll
    for (int mt = 0; mt < 2; ++mt)
#pragma unroll
      for (int nt = 0; nt < 2; ++nt) {
        acc[mt][nt] = mfma16(ah[mt].v, bh[nt].v, acc[mt][nt]);
        acc[mt][nt] = mfma16(ah[mt].v, bl[nt].v, acc[mt][nt]);
        acc[mt][nt] = mfma16(al[mt].v, bh[nt].v, acc[mt][nt]);
      }
  }
#pragma unroll
  for (int mt = 0; mt < 2; ++mt)
#pragma unroll
    for (int nt = 0; nt < 2; ++nt)
#pragma unroll
      for (int q = 0; q < 4; ++q) {
        int grow = rb + mw*32 + mt*16 + lhi*4 + q;
        int gcol = cb + nw*32 + nt*16 + l15;
        float vv = acc[mt][nt][q];
        if (Z)  Z[(long)grow*Hn + gcol] = vv;
        if (ZT) ZT[(long)gcol*Hn + grow] = vv;
        Zb[(long)grow*Hn + gcol] = f2bf(vv);
      }
}

// ---------------------------------------------------------------------------
// k_u2z: X_2 (both halves) + z from xn in ONE pass.
//   fwd rows r<16384:  X2[r] = xn[r]@Bm^T + (r-8>=0   ? xn[r-8]@W1^T : 0)
//   bwd rows r>=16384: X2[r] = xn[r']@Bm^T + (r'+8<16384? xn[r'+8]@W1^T : 0)
//   z[r'] = xn[r']@gw^T  (fwd blocks only)
// 128x128 tile, 4 waves 2x2, 5 staged streams (2A + 3B), 2-buf 80KB,
// stage-early, one barrier/step. grid 1536.
__global__ __launch_bounds__(256) void k_u2z(
    const unsigned short* __restrict__ xn, const unsigned short* __restrict__ Bmb,
    const unsigned short* __restrict__ W1b, const unsigned short* __restrict__ gwb,
    unsigned short* __restrict__ X2, unsigned short* __restrict__ z,
    const unsigned short* __restrict__ zp) {
  constexpr int BUFS = 5 * 4096;                      // shorts per buffer
  __shared__ __align__(16) unsigned short ldsb[2 * BUFS];   // 80 KB

  const int tid = threadIdx.x, lane = tid & 63, w = tid >> 6;
  const int l15 = lane & 15, lhi = lane >> 4;
  const int wr = w >> 1, wc = w & 1;

  const int nwg = gridDim.x;
  const int q8 = nwg >> 3, r8 = nwg & 7, xcd = blockIdx.x & 7, fo = blockIdx.x >> 3;
  const int wg = (xcd < r8 ? xcd*(q8+1) : r8*(q8+1) + (xcd - r8)*q8) + fo;
  const int cb = wg % 6, rbk = wg / 6;
  const long r0  = (long)rbk * 128;                   // global 0..32640
  const long bc0 = (long)cb * 128;
  const int dir = (r0 >= 16384) ? 1 : 0;
  const long r0m = r0 - (long)dir * 16384;            // 0..16256

  const int rowin = lane >> 2, ch = lane & 3;
  long gA0[2]; long gA1[2]; bool vA1[2]; long gB[2]; int lbase[2];
#pragma unroll
  for (int jj = 0; jj < 2; ++jj) {
    const int inst = w*2 + jj;
    const int r = inst*16 + rowin;
    const int c = ch ^ ((r ^ (r >> 2)) & 3);
    lbase[jj] = inst * 512;
    gA0[jj] = (r0m + r) * Hn + c*8;
    long g1 = r0m + r + (dir ? 8 : -8);
    vA1[jj] = (g1 >= 0) && (g1 < 16384);
    gA1[jj] = g1 * Hn + c*8;
    gB[jj]  = (bc0 + r) * Hn + c*8;
  }

  auto stage = [&](int buf, int kt) {
    const int ko = kt * 32;
    unsigned short* dst = ldsb + buf * BUFS;
#pragma unroll
    for (int jj = 0; jj < 2; ++jj) {
      glds16(xn + gA0[jj] + ko, dst + 0*4096 + lbase[jj]);
      glds16(vA1[jj] ? (xn + gA1[jj] + ko) : zp, dst + 1*4096 + lbase[jj]);
      glds16(Bmb + gB[jj] + ko, dst + 2*4096 + lbase[jj]);
      glds16(W1b + gB[jj] + ko, dst + 3*4096 + lbase[jj]);
      glds16(gwb + gB[jj] + ko, dst + 4*4096 + lbase[jj]);
    }
  };

  ffrag acc[4][4] = {};
  ffrag accZ[4][4] = {};
  const int cx = (lhi ^ ((l15 ^ (l15 >> 2)) & 3)) * 8;

  stage(0, 0);
  __syncthreads();
  int cur = 0;
  for (int kt = 0; kt < 24; ++kt) {
    if (kt < 23) stage(cur ^ 1, kt + 1);
    const unsigned short* L = ldsb + cur * BUFS;
    bfrag a0[4], a1[4], b0[4], b1[4], b2[4];
#pragma unroll
    for (int mt = 0; mt < 4; ++mt) {
      const int row = wr*64 + mt*16 + l15;
      a0[mt] = *(const bfrag*)&L[0*4096 + row*32 + cx];
      a1[mt] = *(const bfrag*)&L[1*4096 + row*32 + cx];
    }
#pragma unroll
    for (int nt = 0; nt < 4; ++nt) {
      const int row = wc*64 + nt*16 + l15;
      b0[nt] = *(const bfrag*)&L[2*4096 + row*32 + cx];
      b1[nt] = *(const bfrag*)&L[3*4096 + row*32 + cx];
      b2[nt] = *(const bfrag*)&L[4*4096 + row*32 + cx];
    }
#pragma unroll
    for (int mt = 0; mt < 4; ++mt)
#pragma unroll
      for (int nt = 0; nt < 4; ++nt) {
        acc[mt][nt] = mfma16(a0[mt], b0[nt], acc[mt][nt]);
        acc[mt][nt] = mfma16(a1[mt], b1[nt], acc[mt][nt]);
      }
    if (!dir) {
#pragma unroll
      for (int mt = 0; mt < 4; ++mt)
#pragma unroll
        for (int nt = 0; nt < 4; ++nt)
          accZ[mt][nt] = mfma16(a0[mt], b2[nt], accZ[mt][nt]);
    }
    __syncthreads();
    cur ^= 1;
  }

  // epilogue: which 0 -> X2 (all blocks), which 1 -> z (fwd only)
  float* fl = (float*)ldsb;                 // 64 x FLS f32 = 33792 B <= 80KB
#pragma unroll
  for (int which = 0; which < 2; ++which) {
    if (which == 1 && dir) break;
#pragma unroll
    for (int hh = 0; hh < 2; ++hh) {
      __syncthreads();
      if (wr == hh) {
#pragma unroll
        for (int mt = 0; mt < 4; ++mt)
#pragma unroll
          for (int nt = 0; nt < 4; ++nt)
#pragma unroll
            for (int q = 0; q < 4; ++q)
              fl[(mt*16 + lhi*4 + q)*FLS + wc*64 + nt*16 + l15] =
                  which ? accZ[mt][nt][q] : acc[mt][nt][q];
      }
      __syncthreads();
      for (int i = tid; i < 2048; i += 256) {
        const int row = i >> 5;
        const int cc  = (i & 31) << 2;
        f4 v = *(const f4*)&fl[row*FLS + cc];
        s4v ov;
#pragma unroll
        for (int j = 0; j < 4; ++j) ((unsigned short*)&ov)[j] = f2bf(v[j]);
        if (which == 0) {
          const long go = (r0 + hh*64 + row) * Hn + bc0 + cc;
          *(s4v*)&X2[go] = ov;
        } else {
          const long go = (r0m + hh*64 + row) * Hn + bc0 + cc;
          *(s4v*)&z[go] = ov;
        }
      }
    }
  }
}

// ---------------------------------------------------------------------------
// k_lvl: round-10 proven level pass. 128x256 tile, BK=32, 512 thr (8 waves
// 2x4, wave 64x64), 2-buf 48KB, stage-early, one barrier/step.
// out = res + A0[row -/+ sh] @ B0^T. grid 768.
__global__ __launch_bounds__(512) void k_lvl(
    const unsigned short* __restrict__ A0s, const unsigned short* __restrict__ B0s,
    const unsigned short* __restrict__ res, unsigned short* __restrict__ outb,
    const unsigned short* __restrict__ zp, int sh) {
  constexpr int BUFS = 4096 + 8192;
  __shared__ __align__(16) unsigned short ldsb[2 * BUFS];

  const int tid = threadIdx.x, lane = tid & 63, w = tid >> 6;
  const int l15 = lane & 15, lhi = lane >> 4;
  const int wr = w >> 2, wc = w & 3;               // 2 x 4 wave grid

  const int nwg = gridDim.x;
  const int q8 = nwg >> 3, r8 = nwg & 7, xcd = blockIdx.x & 7, fo = blockIdx.x >> 3;
  const int wg = (xcd < r8 ? xcd*(q8+1) : r8*(q8+1) + (xcd - r8)*q8) + fo;
  const int cb = wg % 3, rbk = wg / 3;
  const long r0  = (long)rbk * 128;
  const long bc0 = (long)cb * 256;
  const int dir = (r0 >= 16384) ? 1 : 0;
  const bool skip = dir ? (r0 >= 32768 - sh) : (r0 + 128 <= sh);

  const int rowin = lane >> 2, ch = lane & 3;
  const int rA = w*16 + rowin;
  const int cswz = ch ^ ((rowin ^ (rowin >> 2)) & 3);
  long gA; bool vA;
  {
    long gr = r0 + rA + (dir ? sh : -sh);
    vA = dir ? (gr < 32768) : (gr >= 0);
    gA = gr * Hn + cswz*8;
  }
  long gB[2];
#pragma unroll
  for (int j = 0; j < 2; ++j)
    gB[j] = (bc0 + j*128 + rA) * Hn + cswz*8;

  auto stage = [&](int buf, int kt) {
    const int ko = kt * 32;
    unsigned short* dst = ldsb + buf * BUFS;
    const unsigned short* g = vA ? (A0s + gA + ko) : zp;
    glds16(g, dst + w*512);
#pragma unroll
    for (int j = 0; j < 2; ++j)
      glds16(B0s + gB[j] + ko, dst + 4096 + j*4096 + w*512);
  };

  ffrag acc[4][4] = {};
  const int cx = (lhi ^ ((l15 ^ (l15 >> 2)) & 3)) * 8;

  if (!skip) {
    stage(0, 0);
    __syncthreads();
    int cur = 0;
    for (int kt = 0; kt < 24; ++kt) {
      if (kt < 23) stage(cur ^ 1, kt + 1);
      const unsigned short* L = ldsb + cur * BUFS;
      bfrag a[4], b[4];
#pragma unroll
      for (int mt = 0; mt < 4; ++mt)
        a[mt] = *(const bfrag*)&L[(wr*64 + mt*16 + l15)*32 + cx];
#pragma unroll
      for (int nt = 0; nt < 4; ++nt)
        b[nt] = *(const bfrag*)&L[4096 + (wc*64 + nt*16 + l15)*32 + cx];
#pragma unroll
      for (int mt = 0; mt < 4; ++mt)
#pragma unroll
        for (int nt = 0; nt < 4; ++nt)
          acc[mt][nt] = mfma16(a[mt], b[nt], acc[mt][nt]);
      __syncthreads();
      cur ^= 1;
    }
  }

  float* fl = (float*)ldsb;
#pragma unroll
  for (int p = 0; p < 4; ++p) {
    __syncthreads();
#pragma unroll
    for (int nt = 0; nt < 4; ++nt)
#pragma unroll
      for (int q = 0; q < 4; ++q)
        fl[(wr*16 + lhi*4 + q)*BLS + wc*64 + nt*16 + l15] = acc[p][nt][q];
    __syncthreads();
    for (int i = tid; i < 2048; i += 512) {
      const int srow = i >> 6;
      const int cc   = (i & 63) << 2;
      f4 v = *(const f4*)&fl[srow*BLS + cc];
      const long grow = r0 + (srow >> 4)*64 + p*16 + (srow & 15);
      const long gcol = bc0 + cc;
      const long go = grow * Hn + gcol;
      s4v rv = *(const s4v*)&res[go];
#pragma unroll
      for (int j = 0; j < 4; ++j) v[j] += bf2f(((unsigned short*)&rv)[j]);
      s4v ov;
#pragma unroll
      for (int j = 0; j < 4; ++j) ((unsigned short*)&ov)[j] = f2bf(v[j]);
      *(s4v*)&outb[go] = ov;
    }
  }
}

// ---------------------------------------------------------------------------
// k_cmb: combine (proven). 128x256 tile, 8 waves 2x4, 2-buf, stage-early.
// out = res[r]+res[r+16384] + (A0[r-sh]+A0[r+16384+sh]) @ B0^T. grid 384.
__global__ __launch_bounds__(512) void k_cmb(
    const unsigned short* __restrict__ A0s, const unsigned short* __restrict__ B0s,
    const unsigned short* __restrict__ res, unsigned short* __restrict__ outb,
    const unsigned short* __restrict__ zp, int sh) {
  constexpr int BUFS = 2 * 4096 + 8192;
  __shared__ __align__(16) unsigned short ldsb[2 * BUFS];

  const int tid = threadIdx.x, lane = tid & 63, w = tid >> 6;
  const int l15 = lane & 15, lhi = lane >> 4;
  const int wr = w >> 2, wc = w & 3;

  const int nwg = gridDim.x;
  const int q8 = nwg >> 3, r8 = nwg & 7, xcd = blockIdx.x & 7, fo = blockIdx.x >> 3;
  const int wg = (xcd < r8 ? xcd*(q8+1) : r8*(q8+1) + (xcd - r8)*q8) + fo;
  const int cb = wg % 3, rbk = wg / 3;
  const long r0  = (long)rbk * 128;
  const long bc0 = (long)cb * 256;

  const int rowin = lane >> 2, ch = lane & 3;
  const int rA = w*16 + rowin;
  const int cswz = ch ^ ((rowin ^ (rowin >> 2)) & 3);
  long gA[2]; bool vA[2];
  { long g0 = r0 + rA - sh;         vA[0] = (g0 >= 0);    gA[0] = g0 * Hn + cswz*8; }
  { long g1 = r0 + rA + 16384 + sh; vA[1] = (g1 < 32768); gA[1] = g1 * Hn + cswz*8; }
  long gB[2];
#pragma unroll
  for (int j = 0; j < 2; ++j)
    gB[j] = (bc0 + j*128 + rA) * Hn + cswz*8;

  auto stage = [&](int buf, int kt) {
    const int ko = kt * 32;
    unsigned short* dst = ldsb + buf * BUFS;
#pragma unroll
    for (int s = 0; s < 2; ++s) {
      const unsigned short* g = vA[s] ? (A0s + gA[s] + ko) : zp;
      glds16(g, dst + s*4096 + w*512);
    }
#pragma unroll
    for (int j = 0; j < 2; ++j)
      glds16(B0s + gB[j] + ko, dst + 2*4096 + j*4096 + w*512);
  };

  ffrag acc[4][4] = {};
  const int cx = (lhi ^ ((l15 ^ (l15 >> 2)) & 3)) * 8;

  stage(0, 0);
  __syncthreads();
  int cur = 0;
  for (int kt = 0; kt < 24; ++kt) {
    if (kt < 23) stage(cur ^ 1, kt + 1);
    const unsigned short* L = ldsb + cur * BUFS;
    bfrag a[2][4], b[4];
#pragma unroll
    for (int mt = 0; mt < 4; ++mt) {
      const int row = wr*64 + mt*16 + l15;
      a[0][mt] = *(const bfrag*)&L[row*32 + cx];
      a[1][mt] = *(const bfrag*)&L[4096 + row*32 + cx];
    }
#pragma unroll
    for (int nt = 0; nt < 4; ++nt) {
      const int row = wc*64 + nt*16 + l15;
      b[nt] = *(const bfrag*)&L[2*4096 + row*32 + cx];
    }
#pragma unroll
    for (int mt = 0; mt < 4; ++mt)
#pragma unroll
      for (int nt = 0; nt < 4; ++nt) {
        acc[mt][nt] = mfma16(a[0][mt], b[nt], acc[mt][nt]);
        acc[mt][nt] = mfma16(a[1][mt], b[nt], acc[mt][nt]);
      }
    __syncthreads();
    cur ^= 1;
  }

  float* fl = (float*)ldsb;
#pragma unroll
  for (int p = 0; p < 4; ++p) {
    __syncthreads();
#pragma unroll
    for (int nt = 0; nt < 4; ++nt)
#pragma unroll
      for (int q = 0; q < 4; ++q)
        fl[(wr*16 + lhi*4 + q)*BLS + wc*64 + nt*16 + l15] = acc[p][nt][q];
    __syncthreads();
    for (int i = tid; i < 2048; i += 512) {
      const int srow = i >> 6;
      const int cc   = (i & 63) << 2;
      f4 v = *(const f4*)&fl[srow*BLS + cc];
      const long grow = r0 + (srow >> 4)*64 + p*16 + (srow & 15);
      const long gcol = bc0 + cc;
      const long go = grow * Hn + gcol;
      s4v ra = *(const s4v*)&res[go];
      s4v rb2 = *(const s4v*)&res[go + (long)16384*Hn];
#pragma unroll
      for (int j = 0; j < 4; ++j)
        v[j] += bf2f(((unsigned short*)&ra)[j]) + bf2f(((unsigned short*)&rb2)[j]);
      s4v ov;
#pragma unroll
      for (int j = 0; j < 4; ++j) ((unsigned short*)&ov)[j] = f2bf(v[j]);
      *(s4v*)&outb[go] = ov;
    }
  }
}

// ---------------------------------------------------------------------------
// k_fin2: out = x + alpha*0.5*(Xsum@Cm^T)*sigmoid(z+gb). 128x128 tile,
// 4 waves, 2-buf 32KB; 4-phase FLS bounce (16.9KB) fits. grid 768.
__global__ __launch_bounds__(256) void k_fin2(
    const unsigned short* __restrict__ A0s, const unsigned short* __restrict__ B0s,
    const unsigned short* __restrict__ z,
    const float* __restrict__ gb, const float* __restrict__ alpha,
    const float* __restrict__ x, float* __restrict__ outf) {
  __shared__ __align__(16) unsigned short ldsb[2 * 8192];   // 32 KB

  const int tid = threadIdx.x, lane = tid & 63, w = tid >> 6;
  const int l15 = lane & 15, lhi = lane >> 4;
  const int wr = w >> 1, wc = w & 1;

  const int nwg = gridDim.x;
  const int q8 = nwg >> 3, r8 = nwg & 7, xcd = blockIdx.x & 7, fo = blockIdx.x >> 3;
  const int wg = (xcd < r8 ? xcd*(q8+1) : r8*(q8+1) + (xcd - r8)*q8) + fo;
  const int cb = wg % 6, rbk = wg / 6;
  const long r0 = (long)rbk * 128;
  const long bc0 = (long)cb * 128;

  const int rowin = lane >> 2, ch = lane & 3;
  long gA[2]; long gB[2]; int lbase[2];
#pragma unroll
  for (int jj = 0; jj < 2; ++jj) {
    const int inst = w*2 + jj;
    const int r = inst*16 + rowin;
    const int c = ch ^ ((r ^ (r >> 2)) & 3);
    lbase[jj] = inst * 512;
    gA[jj] = (r0 + r) * Hn + c*8;
    gB[jj] = (bc0 + r) * Hn + c*8;
  }

  auto stage = [&](int buf, int kt) {
    const int ko = kt * 32;
    unsigned short* dst = ldsb + buf * 8192;
#pragma unroll
    for (int jj = 0; jj < 2; ++jj) {
      glds16(A0s + gA[jj] + ko, dst + lbase[jj]);
      glds16(B0s + gB[jj] + ko, dst + 4096 + lbase[jj]);
    }
  };

  ffrag acc[4][4] = {};
  const int cx = (lhi ^ ((l15 ^ (l15 >> 2)) & 3)) * 8;

  stage(0, 0);
  __syncthreads();
  int cur = 0;
  for (int kt = 0; kt < 24; ++kt) {
    if (kt < 23) stage(cur ^ 1, kt + 1);
    const unsigned short* L = ldsb + cur * 8192;
    bfrag a[4], b[4];
#pragma unroll
    for (int mt = 0; mt < 4; ++mt)
      a[mt] = *(const bfrag*)&L[(wr*64 + mt*16 + l15)*32 + cx];
#pragma unroll
    for (int nt = 0; nt < 4; ++nt)
      b[nt] = *(const bfrag*)&L[4096 + (wc*64 + nt*16 + l15)*32 + cx];
#pragma unroll
    for (int mt = 0; mt < 4; ++mt)
#pragma unroll
      for (int nt = 0; nt < 4; ++nt)
        acc[mt][nt] = mfma16(a[mt], b[nt], acc[mt][nt]);
    __syncthreads();
    cur ^= 1;
  }

  const float al = alpha[0];
  float* fl = (float*)ldsb;
#pragma unroll
  for (int p = 0; p < 4; ++p) {
    __syncthreads();
    if (wr == (p >> 1)) {
#pragma unroll
      for (int mt2 = 0; mt2 < 2; ++mt2) {
        const int mt = (p & 1)*2 + mt2;
#pragma unroll
        for (int nt = 0; nt < 4; ++nt)
#pragma unroll
          for (int q = 0; q < 4; ++q)
            fl[(mt2*16 + lhi*4 + q)*FLS + wc*64 + nt*16 + l15] = acc[mt][nt][q];
      }
    }
    __syncthreads();
    for (int i = tid; i < 1024; i += 256) {
      const int row = i >> 5;
      const int cc  = (i & 31) << 2;
      f4 v = *(const f4*)&fl[row*FLS + cc];
      const long grow = r0 + p*32 + row;
      const long gcol = bc0 + cc;
      const long go = grow * Hn + gcol;
      s4v zv = *(const s4v*)&z[go];
      f4 gbv = *(const f4*)&gb[gcol];
      const long t = grow >> 3, b = grow & 7;
      const long o = (b*2048 + t)*Hn + gcol;
      f4 xv = *(const f4*)&x[o];
      f4 ov;
#pragma unroll
      for (int j = 0; j < 4; ++j) {
        float zz = bf2f(((unsigned short*)&zv)[j]) + gbv[j];
        float g = 1.0f / (1.0f + __expf(-zz));
        ov[j] = xv[j] + al * 0.5f * v[j] * g;
      }
      *(f4*)&outf[o] = ov;
    }
  }
}

// ---------------------------------------------------------------------------
extern "C" void kernel_launch(void* const* d_in, const int* in_sizes, int n_in,
                              void* d_out, int out_size, void* d_ws, size_t ws_size,
                              hipStream_t stream) {
  const float* x     = (const float*)d_in[0];
  const float* scale = (const float*)d_in[1];
  const float* U     = (const float*)d_in[2];
  const float* V     = (const float*)d_in[3];
  const float* S     = (const float*)d_in[4];
  const float* Bm    = (const float*)d_in[5];
  const float* Cm    = (const float*)d_in[6];
  const float* gw    = (const float*)d_in[7];
  const float* gb    = (const float*)d_in[8];
  const float* alpha = (const float*)d_in[9];
  float* out = (float*)d_out;

  char* p = (char*)d_ws;
  auto alloc = [&](size_t sz) { char* r = p; p += (sz + 255) & ~(size_t)255; return r; };

  const size_t SZ_X  = (size_t)32768 * Hn * sizeof(unsigned short);  // 50.3MB
  const size_t SZ_BF = (size_t)16384 * Hn * sizeof(unsigned short);  // 25.2MB
  const size_t SZ_M  = (size_t)Hn * Hn * sizeof(float);              // 2.36MB
  const size_t SZ_MB = (size_t)Hn * Hn * sizeof(unsigned short);     // 1.18MB

  unsigned short* xn   = (unsigned short*)alloc(SZ_BF);
  unsigned short* zbuf = (unsigned short*)alloc(SZ_BF);
  unsigned short* XA = (unsigned short*)alloc(SZ_X);
  unsigned short* XB = (unsigned short*)alloc(SZ_X);
  float* Af  = (float*)alloc(SZ_M);
  float* AfT = (float*)alloc(SZ_M);
  float* P1  = (float*)alloc(SZ_M);
  float* P1T = (float*)alloc(SZ_M);
  float* P2  = (float*)alloc(SZ_M);
  float* P2T = (float*)alloc(SZ_M);
  unsigned short* Abf = (unsigned short*)alloc(SZ_MB);
  unsigned short* Ab[10];                      // A^2..A^1024 bf16
  for (int i = 0; i < 10; ++i) Ab[i] = (unsigned short*)alloc(SZ_MB);
  unsigned short* Bmb = (unsigned short*)alloc(SZ_MB);
  unsigned short* Cmb = (unsigned short*)alloc(SZ_MB);
  unsigned short* gwb = (unsigned short*)alloc(SZ_MB);
  unsigned short* W1b = (unsigned short*)alloc(SZ_MB);
  unsigned short* zp  = (unsigned short*)alloc(1024 * sizeof(unsigned short));

  // BmTf (f32) aliases P2: written by k_abuild, consumed by k_mul BEFORE
  // k_sq #2 first writes P2.
  float* BmTf = P2;

  if ((size_t)(p - (char*)d_ws) > ws_size) return;  // workspace too small

  k_abuild<<<dim3(768, 4), 256, 0, stream>>>(U, V, S, Bm, Cm, gw,
      Af, AfT, Abf, Bmb, BmTf, Cmb, gwb, zp);
  k_rms<<<4096, 256, 0, stream>>>(x, scale, xn);

  // k_sq #1: A -> A^2 (P1).  Then W1 = A @ Bm (uses Af + BmTf==P2, before
  // k_sq #2 overwrites P2).
  k_sq<<<dim3(12, 6), 512, 0, stream>>>(Af, AfT, P1, P1T, Ab[0]);
  k_mul<<<dim3(12, 6), 512, 0, stream>>>(Af, BmTf, nullptr, nullptr, W1b);

  // remaining squaring chain: A^4 .. A^1024
  const float* sx = P1; const float* sxt = P1T;
  float* za = P2; float* zat = P2T; float* zb = P1; float* zbt = P1T;
  for (int i = 1; i < 10; ++i) {
    k_sq<<<dim3(12, 6), 512, 0, stream>>>(sx, sxt, za, zat, Ab[i]);
    sx = za; sxt = zat;
    float* t1 = za; float* t2 = zat; za = zb; zat = zbt; zb = t1; zbt = t2;
  }

  // X_2 (both halves) + z in one pass
  k_u2z<<<1536, 256, 0, stream>>>(xn, Bmb, W1b, gwb, XA, zbuf, zp);

  // doubling levels k=2..512 (W = A^{2^i}, shift 8*2^i rows)
  unsigned short* src = XA; unsigned short* dst = XB;
  for (int i = 1; i < 10; ++i) {
    k_lvl<<<768, 512, 0, stream>>>(src, Ab[i-1], src, dst, zp, 8 << i);
    unsigned short* t = src; src = dst; dst = t;
  }
  // src holds X_1024 (both dirs). Combine (k=1024) + fwd/bwd sum:
  unsigned short* xsum = (src == XA) ? XB : XA;
  k_cmb<<<384, 512, 0, stream>>>(src, Ab[9], src, xsum, zp, 8192);

  // out = x + alpha*0.5*(Xsum@Cm^T)*sigmoid(z+gb)
  k_fin2<<<768, 256, 0, stream>>>(xsum, Cmb, zbuf, gb, alpha, x, out);
}

// Round 16
// 1226.439 us; speedup vs baseline: 1.0896x; 1.0896x over previous
//
#include <hip/hip_runtime.h>

// ---------------------------------------------------------------------------
// BiSSM global block, MI355X — round 16: round-10 best config (1240us) +
// k_sq retiled 64x64/grid(12,12) (was 72 blocks -> 144; chain was ~150us).
//   u[t]    = xn[t]@Bm^T (dup to fwd+bwd halves)            k_lvl<0>
//   X_2k[t] = X_k[t] + X_k[t-/+k]@(A^k)^T, k=1..512          k_lvl<1> x10
//   Xsum[t] = X_f[t]+X_f[t-1024]@W + X_b[t]+X_b[t+1024]@W    k_lvl<2> (W=A^1024)
//   out     = x + alpha*0.5*(Xsum@Cm^T)*sigmoid(xn@gw^T+gb)  k_fin (dual GEMM)
// k_lvl: 128x256 block tile, BK=32, 512 thr (8 waves 2x4, wave=64x64), 2-buf
// LDS (48KB M0/1; 64KB M2), stage-early + ONE __syncthreads per K-step.
// global_load_lds(16B), chunk swizzle c^((r^(r>>2))&3) both sides.
// Epilogue: 4 phases 32x256 f32 bounce (stride BLS) -> vectorized I/O.
// k_fin: 4-stream fused final (Xsum,xn,Cm,gw staged; 64KB).
// Powers A^2..A^1024: hi/lo-bf16 f32 squaring chain (k_sq x10, 3-pass).
// ---------------------------------------------------------------------------

typedef short  bfrag __attribute__((ext_vector_type(8)));   // 8 x bf16
typedef float  ffrag __attribute__((ext_vector_type(4)));   // mfma acc
typedef float  f4    __attribute__((ext_vector_type(4)));
typedef short  s4v   __attribute__((ext_vector_type(4)));   // 4 x bf16

#define DEV static __device__ __forceinline__
#define Hn 768
#define FLS 132   // k_fin bounce stride (128+4)
#define BLS 260   // k_lvl bounce stride (256+4)

DEV unsigned short f2bf(float f) {
  unsigned u = __float_as_uint(f);
  u += 0x7fffu + ((u >> 16) & 1u);            // round-to-nearest-even
  return (unsigned short)(u >> 16);
}
DEV float bf2f(unsigned short s) { return __uint_as_float(((unsigned)s) << 16); }

DEV ffrag mfma16(bfrag a, bfrag b, ffrag c) {
  return __builtin_amdgcn_mfma_f32_16x16x32_bf16(a, b, c, 0, 0, 0);
}

DEV void glds16(const unsigned short* g, unsigned short* l) {
  __builtin_amdgcn_global_load_lds(
      (const __attribute__((address_space(1))) unsigned int*)g,
      (__attribute__((address_space(3))) unsigned int*)l, 16, 0, 0);
}

union BF8 { bfrag v; unsigned short u[8]; };

// ---------------------------------------------------------------------------
// k_abuild: gridDim = (768, 4); task = blockIdx.y
__global__ __launch_bounds__(256) void k_abuild(
    const float* __restrict__ U, const float* __restrict__ V,
    const float* __restrict__ S, const float* __restrict__ Bm,
    const float* __restrict__ Cm, const float* __restrict__ gw,
    float* __restrict__ Af, float* __restrict__ AfT,
    unsigned short* __restrict__ Abf,
    unsigned short* __restrict__ Bmb, unsigned short* __restrict__ Cmb,
    unsigned short* __restrict__ gwb, unsigned short* __restrict__ zp) {
  int i = blockIdx.x;
  int task = blockIdx.y;
  if (task == 0) {
    float u0 = U[i*4+0], u1 = U[i*4+1], u2 = U[i*4+2], u3 = U[i*4+3];
    for (int j = threadIdx.x; j < Hn; j += 256) {
      float a = u0*V[j*4+0] + u1*V[j*4+1] + u2*V[j*4+2] + u3*V[j*4+3]
              + S[i*Hn+j] - S[j*Hn+i];
      if (i == j) a += -(float)(i+1) / 768.0f;
      Af[i*Hn+j]  = a;
      AfT[j*Hn+i] = a;
      Abf[i*Hn+j] = f2bf(a);
    }
    if (i == 0) for (int j = threadIdx.x; j < 1024; j += 256) zp[j] = 0;
  } else {
    const float* src = (task==1) ? Bm : (task==2) ? Cm : gw;
    unsigned short* dst = (task==1) ? Bmb : (task==2) ? Cmb : gwb;
    for (int j = threadIdx.x; j < Hn; j += 256) dst[i*Hn+j] = f2bf(src[i*Hn+j]);
  }
}

// ---------------------------------------------------------------------------
// k_rms: one wave per row (row = b*2048 + t); write xn in (t,b) order, bf16.
__global__ __launch_bounds__(256) void k_rms(
    const float* __restrict__ x, const float* __restrict__ scale,
    unsigned short* __restrict__ xn) {
  int row  = blockIdx.x * 4 + (threadIdx.x >> 6);
  int lane = threadIdx.x & 63;
  int b = row >> 11, t = row & 2047;
  const float* xr = x + (long)row * Hn;
  float v[12];
  float ss = 0.f;
#pragma unroll
  for (int j = 0; j < 12; ++j) { v[j] = xr[lane + j*64]; ss += v[j]*v[j]; }
#pragma unroll
  for (int off = 1; off < 64; off <<= 1) ss += __shfl_xor(ss, off);
  float inv = 1.0f / sqrtf(ss / 768.0f + 1e-8f);
  unsigned short* dst = xn + ((long)t * 8 + b) * Hn;
#pragma unroll
  for (int j = 0; j < 12; ++j) dst[lane + j*64] = f2bf(v[j] * inv * scale[lane + j*64]);
}

// ---------------------------------------------------------------------------
// k_sq: Z = X @ X, hi/lo bf16 (3 passes). Writes Z rm + Z^T rm f32 + bf16.
// RETILED: 64x64 tile, 256 thr (4 waves 2x2), grid (12,12) = 144 blocks
// (was 64x128/(12,6)=72 blocks -> 72% of CUs idle). Same math.
__global__ __launch_bounds__(256) void k_sq(
    const float* __restrict__ X, const float* __restrict__ XT,
    float* __restrict__ Z, float* __restrict__ ZT,
    unsigned short* __restrict__ Zbf) {
  int tid = threadIdx.x, lane = tid & 63, w = tid >> 6;
  int mw = w >> 1, nw = w & 1, l15 = lane & 15, lhi = lane >> 4;
  int rb = blockIdx.x * 64, cb = blockIdx.y * 64;
  ffrag acc[2][2] = {};
  for (int kt = 0; kt < 24; ++kt) {
    int k0 = kt*32 + lhi*8;
    BF8 ah[2], al[2], bh[2], bl[2];
#pragma unroll
    for (int mt = 0; mt < 2; ++mt) {
      const f4* p = (const f4*)(X + (long)(rb + mw*32 + mt*16 + l15) * Hn + k0);
      f4 x0 = p[0], x1 = p[1];
#pragma unroll
      for (int j = 0; j < 8; ++j) {
        float f = (j < 4) ? x0[j] : x1[j-4];
        unsigned short h = f2bf(f);
        ah[mt].u[j] = h; al[mt].u[j] = f2bf(f - bf2f(h));
      }
    }
#pragma unroll
    for (int nt = 0; nt < 2; ++nt) {
      const f4* p = (const f4*)(XT + (long)(cb + nw*32 + nt*16 + l15) * Hn + k0);
      f4 x0 = p[0], x1 = p[1];
#pragma unroll
      for (int j = 0; j < 8; ++j) {
        float f = (j < 4) ? x0[j] : x1[j-4];
        unsigned short h = f2bf(f);
        bh[nt].u[j] = h; bl[nt].u[j] = f2bf(f - bf2f(h));
      }
    }
#pragma unroll
    for (int mt = 0; mt < 2; ++mt)
#pragma unroll
      for (int nt = 0; nt < 2; ++nt) {
        acc[mt][nt] = mfma16(ah[mt].v, bh[nt].v, acc[mt][nt]);
        acc[mt][nt] = mfma16(ah[mt].v, bl[nt].v, acc[mt][nt]);
        acc[mt][nt] = mfma16(al[mt].v, bh[nt].v, acc[mt][nt]);
      }
  }
#pragma unroll
  for (int mt = 0; mt < 2; ++mt)
#pragma unroll
    for (int nt = 0; nt < 2; ++nt)
#pragma unroll
      for (int q = 0; q < 4; ++q) {
        int grow = rb + mw*32 + mt*16 + lhi*4 + q;
        int gcol = cb + nw*32 + nt*16 + l15;
        float vv = acc[mt][nt][q];
        Z[(long)grow*Hn + gcol] = vv;
        ZT[(long)gcol*Hn + grow] = vv;
        Zbf[(long)grow*Hn + gcol] = f2bf(vv);
      }
}

// ---------------------------------------------------------------------------
// k_lvl<MODE>: 128x256 block tile, BK=32, 24 K-steps, 512 thr (8 waves 2x4,
// wave tile 64x64). 2-buf LDS, stage-early, ONE __syncthreads per step.
// MODE 0 (u):      out = A0 @ B0^T, dup-write both halves.        grid 384
// MODE 1 (level):  out = res + A0[r -/+ sh] @ B0^T.               grid 768
// MODE 2 (combine):out = res[r]+res[r+16384]
//                        + (A0[r-sh]+A0[r+16384+sh]) @ B0^T.      grid 384
template<int MODE>
__global__ __launch_bounds__(512) void k_lvl(
    const unsigned short* __restrict__ A0s, const unsigned short* __restrict__ B0s,
    const unsigned short* __restrict__ res, unsigned short* __restrict__ outb,
    const unsigned short* __restrict__ zp, int sh) {
  constexpr int NS   = (MODE == 2) ? 2 : 1;        // A streams
  constexpr int BUFS = NS * 4096 + 8192;           // shorts per buffer
  __shared__ __align__(16) unsigned short ldsb[2 * BUFS];

  const int tid = threadIdx.x, lane = tid & 63, w = tid >> 6;
  const int l15 = lane & 15, lhi = lane >> 4;
  const int wr = w >> 2, wc = w & 3;               // 2 x 4 wave grid

  // XCD-aware bijective block swizzle (m204), col-fast decompose (ncol=3).
  const int nwg = gridDim.x;
  const int q8 = nwg >> 3, r8 = nwg & 7, xcd = blockIdx.x & 7, fo = blockIdx.x >> 3;
  const int wg = (xcd < r8 ? xcd*(q8+1) : r8*(q8+1) + (xcd - r8)*q8) + fo;
  const int cb = wg % 3, rbk = wg / 3;
  const long r0  = (long)rbk * 128;
  const long bc0 = (long)cb * 256;
  const int dir = (MODE == 1 && r0 >= 16384) ? 1 : 0;

  bool skip = false;
  if (MODE == 1)
    skip = dir ? (r0 >= 32768 - sh) : (r0 + 128 <= sh);

  // staging: A tile is 128x32 (8KB) = 1 glds16/thread; B tile 256x32 = 2.
  const int rowin = lane >> 2, ch = lane & 3;
  const int rA = w*16 + rowin;
  const int cswz = ch ^ ((rowin ^ (rowin >> 2)) & 3);  // row%16 = rowin
  long gA[NS]; bool vA[NS];
#pragma unroll
  for (int s = 0; s < NS; ++s) {
    long gr; bool ok = true;
    if (MODE == 0) {
      gr = r0 + rA;
    } else if (MODE == 1) {
      gr = r0 + rA + (dir ? sh : -sh);
      ok = dir ? (gr < 32768) : (gr >= 0);
    } else {
      if (s == 0) { gr = r0 + rA - sh;         ok = (gr >= 0);    }
      else        { gr = r0 + rA + 16384 + sh; ok = (gr < 32768); }
    }
    vA[s] = ok; gA[s] = gr * Hn + cswz*8;
  }
  long gB[2];
#pragma unroll
  for (int j = 0; j < 2; ++j)
    gB[j] = (bc0 + j*128 + rA) * Hn + cswz*8;

  auto stage = [&](int buf, int kt) {
    const int ko = kt * 32;
    unsigned short* dst = ldsb + buf * BUFS;
#pragma unroll
    for (int s = 0; s < NS; ++s) {
      const unsigned short* g = vA[s] ? (A0s + gA[s] + ko) : zp;
      glds16(g, dst + s*4096 + w*512);
    }
#pragma unroll
    for (int j = 0; j < 2; ++j)
      glds16(B0s + gB[j] + ko, dst + NS*4096 + j*4096 + w*512);
  };

  ffrag acc[4][4] = {};
  const int cx = (lhi ^ ((l15 ^ (l15 >> 2)) & 3)) * 8;   // swizzled read chunk

  if (!skip) {
    stage(0, 0);
    __syncthreads();
    int cur = 0;
    for (int kt = 0; kt < 24; ++kt) {
      if (kt < 23) stage(cur ^ 1, kt + 1);   // issue next tile BEFORE compute
      const unsigned short* L = ldsb + cur * BUFS;
      bfrag a[NS][4], b[4];
#pragma unroll
      for (int mt = 0; mt < 4; ++mt) {
        const int row = wr*64 + mt*16 + l15;
#pragma unroll
        for (int s = 0; s < NS; ++s)
          a[s][mt] = *(const bfrag*)&L[s*4096 + row*32 + cx];
      }
#pragma unroll
      for (int nt = 0; nt < 4; ++nt) {
        const int row = wc*64 + nt*16 + l15;
        b[nt] = *(const bfrag*)&L[NS*4096 + row*32 + cx];
      }
#pragma unroll
      for (int mt = 0; mt < 4; ++mt)
#pragma unroll
        for (int nt = 0; nt < 4; ++nt) {
          acc[mt][nt] = mfma16(a[0][mt], b[nt], acc[mt][nt]);
          if (NS == 2) acc[mt][nt] = mfma16(a[1][mt], b[nt], acc[mt][nt]);
        }
      __syncthreads();                       // staged tile ready; reads done
      cur ^= 1;
    }
  }

  // ---- epilogue: 4 phases; phase p bounces acc[p] (32 rows x 256 f32) ----
  float* fl = (float*)ldsb;                  // 32 x BLS f32 = 33280 B
#pragma unroll
  for (int p = 0; p < 4; ++p) {
    __syncthreads();
#pragma unroll
    for (int nt = 0; nt < 4; ++nt)
#pragma unroll
      for (int q = 0; q < 4; ++q)
        fl[(wr*16 + lhi*4 + q)*BLS + wc*64 + nt*16 + l15] = acc[p][nt][q];
    __syncthreads();
    for (int i = tid; i < 2048; i += 512) {
      const int srow = i >> 6;               // 0..31
      const int cc   = (i & 63) << 2;        // 0..252
      f4 v = *(const f4*)&fl[srow*BLS + cc];
      const long grow = r0 + (srow >> 4)*64 + p*16 + (srow & 15);
      const long gcol = bc0 + cc;
      const long go = grow * Hn + gcol;
      if (MODE == 0) {
        s4v ov;
#pragma unroll
        for (int j = 0; j < 4; ++j) ((unsigned short*)&ov)[j] = f2bf(v[j]);
        *(s4v*)&outb[go] = ov;
        *(s4v*)&outb[go + (long)16384*Hn] = ov;
      } else if (MODE == 1) {
        s4v rv = *(const s4v*)&res[go];
#pragma unroll
        for (int j = 0; j < 4; ++j) v[j] += bf2f(((unsigned short*)&rv)[j]);
        s4v ov;
#pragma unroll
        for (int j = 0; j < 4; ++j) ((unsigned short*)&ov)[j] = f2bf(v[j]);
        *(s4v*)&outb[go] = ov;
      } else {
        s4v ra = *(const s4v*)&res[go];
        s4v rb2 = *(const s4v*)&res[go + (long)16384*Hn];
#pragma unroll
        for (int j = 0; j < 4; ++j)
          v[j] += bf2f(((unsigned short*)&ra)[j]) + bf2f(((unsigned short*)&rb2)[j]);
        s4v ov;
#pragma unroll
        for (int j = 0; j < 4; ++j) ((unsigned short*)&ov)[j] = f2bf(v[j]);
        *(s4v*)&outb[go] = ov;
      }
    }
  }
}

// ---------------------------------------------------------------------------
// k_fin: fused final. 128x128 tile, BK=32, 256 thr (4 waves 2x2, wave 64x64).
// 2-buf, vmcnt(0)+barrier+stage(kt+1).
// outf = x + alpha*0.5*(A0@B0^T) * sigmoid(A1@B1^T + gb)   (row = t*8+b)
__global__ __launch_bounds__(256) void k_fin(
    const unsigned short* __restrict__ A0s, const unsigned short* __restrict__ A1s,
    const unsigned short* __restrict__ B0s, const unsigned short* __restrict__ B1s,
    const unsigned short* __restrict__ zp,
    const float* __restrict__ gb, const float* __restrict__ alpha,
    const float* __restrict__ x, float* __restrict__ outf) {
  __shared__ __align__(16) char smem[2 * 4 * 8192];
  unsigned short* ldsb = (unsigned short*)smem;

  const int tid = threadIdx.x, lane = tid & 63, w = tid >> 6;
  const int l15 = lane & 15, lhi = lane >> 4;
  const int wr = w >> 1, wc = w & 1;

  const int nwg = gridDim.x;
  const int q8 = nwg >> 3, r8 = nwg & 7, xcd = blockIdx.x & 7, fo = blockIdx.x >> 3;
  const int wg = (xcd < r8 ? xcd*(q8+1) : r8*(q8+1) + (xcd - r8)*q8) + fo;
  const int cb = wg % 6, rbk = wg / 6;
  const long r0 = (long)rbk * 128;
  const long bc0 = (long)cb * 128;

  const int rowin = lane >> 2, ch = lane & 3;
  long gA[2][2]; long gB[2][2]; int lbase[2];
#pragma unroll
  for (int jj = 0; jj < 2; ++jj) {
    const int inst = w*2 + jj;
    const int r = inst*16 + rowin;
    const int c = ch ^ ((r ^ (r >> 2)) & 3);
    lbase[jj] = inst * 512;
    gA[0][jj] = (r0 + r) * Hn + c*8;
    gA[1][jj] = gA[0][jj];
    gB[0][jj] = (bc0 + r) * Hn + c*8;
    gB[1][jj] = gB[0][jj];
  }

  auto stage = [&](int buf, int kt) {
    const int ko = kt * 32;
    unsigned short* dst = ldsb + buf * 16384;
#pragma unroll
    for (int jj = 0; jj < 2; ++jj) {
      glds16(A0s + gA[0][jj] + ko, dst + 0*4096 + lbase[jj]);
      glds16(A1s + gA[1][jj] + ko, dst + 1*4096 + lbase[jj]);
      glds16(B0s + gB[0][jj] + ko, dst + 2*4096 + lbase[jj]);
      glds16(B1s + gB[1][jj] + ko, dst + 3*4096 + lbase[jj]);
    }
  };

  ffrag acc[4][4] = {};
  ffrag accZ[4][4] = {};
  const int cx = (lhi ^ ((l15 ^ (l15 >> 2)) & 3)) * 8;

  stage(0, 0);
  int cur = 0;
  for (int kt = 0; kt < 24; ++kt) {
    asm volatile("s_waitcnt vmcnt(0)" ::: "memory");
    __builtin_amdgcn_s_barrier();
    if (kt < 23) stage(cur ^ 1, kt + 1);
    const unsigned short* L = ldsb + cur * 16384;
    bfrag a[2][4], b0[4], b1[4];
#pragma unroll
    for (int mt = 0; mt < 4; ++mt) {
      const int row = wr*64 + mt*16 + l15;
      a[0][mt] = *(const bfrag*)&L[row*32 + cx];
      a[1][mt] = *(const bfrag*)&L[4096 + row*32 + cx];
    }
#pragma unroll
    for (int nt = 0; nt < 4; ++nt) {
      const int row = wc*64 + nt*16 + l15;
      b0[nt] = *(const bfrag*)&L[2*4096 + row*32 + cx];
      b1[nt] = *(const bfrag*)&L[3*4096 + row*32 + cx];
    }
#pragma unroll
    for (int mt = 0; mt < 4; ++mt)
#pragma unroll
      for (int nt = 0; nt < 4; ++nt) {
        acc[mt][nt]  = mfma16(a[0][mt], b0[nt], acc[mt][nt]);
        accZ[mt][nt] = mfma16(a[1][mt], b1[nt], accZ[mt][nt]);
      }
    cur ^= 1;
  }

  // gate in fragment layout
  const float al = alpha[0];
  float gvals[4];
#pragma unroll
  for (int nt = 0; nt < 4; ++nt) gvals[nt] = gb[bc0 + wc*64 + nt*16 + l15];
#pragma unroll
  for (int mt = 0; mt < 4; ++mt)
#pragma unroll
    for (int nt = 0; nt < 4; ++nt)
#pragma unroll
      for (int q = 0; q < 4; ++q) {
        float z = accZ[mt][nt][q] + gvals[nt];
        float g = 1.0f / (1.0f + __expf(-z));
        acc[mt][nt][q] *= al * 0.5f * g;
      }

  float* fl = (float*)smem;                 // 64 x FLS f32
#pragma unroll
  for (int hh = 0; hh < 2; ++hh) {
    __syncthreads();
    if (wr == hh) {
#pragma unroll
      for (int mt = 0; mt < 4; ++mt)
#pragma unroll
        for (int nt = 0; nt < 4; ++nt)
#pragma unroll
          for (int q = 0; q < 4; ++q)
            fl[(mt*16 + lhi*4 + q)*FLS + wc*64 + nt*16 + l15] = acc[mt][nt][q];
    }
    __syncthreads();
    for (int i = tid; i < 2048; i += 256) {
      const int row = i >> 5;
      const int cc  = (i & 31) << 2;
      f4 v = *(const f4*)&fl[row*FLS + cc];
      const long grow = r0 + hh*64 + row;
      const long gcol = bc0 + cc;
      const long t = grow >> 3, b = grow & 7;
      const long o = (b*2048 + t)*Hn + gcol;
      f4 xv = *(const f4*)&x[o];
      f4 ov;
#pragma unroll
      for (int j = 0; j < 4; ++j) ov[j] = xv[j] + v[j];
      *(f4*)&outf[o] = ov;
    }
  }
}

// ---------------------------------------------------------------------------
extern "C" void kernel_launch(void* const* d_in, const int* in_sizes, int n_in,
                              void* d_out, int out_size, void* d_ws, size_t ws_size,
                              hipStream_t stream) {
  const float* x     = (const float*)d_in[0];
  const float* scale = (const float*)d_in[1];
  const float* U     = (const float*)d_in[2];
  const float* V     = (const float*)d_in[3];
  const float* S     = (const float*)d_in[4];
  const float* Bm    = (const float*)d_in[5];
  const float* Cm    = (const float*)d_in[6];
  const float* gw    = (const float*)d_in[7];
  const float* gb    = (const float*)d_in[8];
  const float* alpha = (const float*)d_in[9];
  float* out = (float*)d_out;

  char* p = (char*)d_ws;
  auto alloc = [&](size_t sz) { char* r = p; p += (sz + 255) & ~(size_t)255; return r; };

  const size_t SZ_X  = (size_t)32768 * Hn * sizeof(unsigned short);  // 50.3MB
  const size_t SZ_BF = (size_t)16384 * Hn * sizeof(unsigned short);  // 25.2MB
  const size_t SZ_M  = (size_t)Hn * Hn * sizeof(float);              // 2.36MB
  const size_t SZ_MB = (size_t)Hn * Hn * sizeof(unsigned short);     // 1.18MB

  unsigned short* xn = (unsigned short*)alloc(SZ_BF);
  unsigned short* XA = (unsigned short*)alloc(SZ_X);
  unsigned short* XB = (unsigned short*)alloc(SZ_X);
  float* Af  = (float*)alloc(SZ_M);
  float* AfT = (float*)alloc(SZ_M);
  float* P1  = (float*)alloc(SZ_M);
  float* P1T = (float*)alloc(SZ_M);
  float* P2  = (float*)alloc(SZ_M);
  float* P2T = (float*)alloc(SZ_M);
  unsigned short* Abf = (unsigned short*)alloc(SZ_MB);
  unsigned short* Ab[10];                      // A^2..A^1024 bf16
  for (int i = 0; i < 10; ++i) Ab[i] = (unsigned short*)alloc(SZ_MB);
  unsigned short* Bmb = (unsigned short*)alloc(SZ_MB);
  unsigned short* Cmb = (unsigned short*)alloc(SZ_MB);
  unsigned short* gwb = (unsigned short*)alloc(SZ_MB);
  unsigned short* zp  = (unsigned short*)alloc(1024 * sizeof(unsigned short));

  if ((size_t)(p - (char*)d_ws) > ws_size) return;  // workspace too small

  k_abuild<<<dim3(768, 4), 256, 0, stream>>>(U, V, S, Bm, Cm, gw,
      Af, AfT, Abf, Bmb, Cmb, gwb, zp);
  k_rms<<<4096, 256, 0, stream>>>(x, scale, xn);

  // squaring chain: A -> A^2 -> ... -> A^1024 (bf16 emitted each step)
  const float* sx = Af; const float* sxt = AfT;
  float* za = P1; float* zat = P1T; float* zb = P2; float* zbt = P2T;
  for (int i = 0; i < 10; ++i) {
    k_sq<<<dim3(12, 12), 256, 0, stream>>>(sx, sxt, za, zat, Ab[i]);
    sx = za; sxt = zat;
    float* t1 = za; float* t2 = zat; za = zb; zat = zbt; zb = t1; zbt = t2;
  }

  // u = xn@Bm^T, duplicated into fwd+bwd halves of XA   (X_1)
  k_lvl<0><<<384, 512, 0, stream>>>(xn, Bmb, nullptr, XA, zp, 0);

  // doubling levels k=1..512 (shift sh=8k rows)
  unsigned short* src = XA; unsigned short* dst = XB;
  for (int i = 0; i < 10; ++i) {
    const unsigned short* W = (i == 0) ? Abf : Ab[i-1];
    k_lvl<1><<<768, 512, 0, stream>>>(src, W, src, dst, zp, 8 << i);
    unsigned short* t = src; src = dst; dst = t;
  }
  // src = XA holds X_1024 (both dirs). Combine (k=1024) + fwd/bwd sum -> XB:
  k_lvl<2><<<384, 512, 0, stream>>>(src, Ab[9], src, XB, zp, 8192);

  // out = x + alpha*0.5*(Xsum@Cm^T)*sigmoid(xn@gw^T+gb)
  k_fin<<<768, 256, 0, stream>>>(XB, xn, Cmb, gwb, zp, gb, alpha, x, out);
}